// Round 3
// baseline (393.897 us; speedup 1.0000x reference)
//
#include <hip/hip_runtime.h>
#include <cstdint>
#include <cstddef>

// ---------- types ----------
typedef __attribute__((ext_vector_type(8))) __bf16 bf16x8;
typedef __attribute__((ext_vector_type(4))) float f32x4;
typedef __attribute__((ext_vector_type(4))) unsigned short u16x4;

__device__ __forceinline__ unsigned short f2bf(float f) {
  unsigned int u = __builtin_bit_cast(unsigned int, f);
  u += 0x7fffu + ((u >> 16) & 1u);           // RNE
  return (unsigned short)(u >> 16);
}
__device__ __forceinline__ float bf2f(unsigned short u) {
  return __builtin_bit_cast(float, ((unsigned int)u) << 16);
}

// ---------- batched weight cast+transpose: W[K][N] f32 -> WT[Npad][K] bf16 ----------
// 64x64 tiles, f32x4 loads, f32 LDS [64][65], u16x4 stores (8B/lane both sides).
__global__ __launch_bounds__(256) void wcast_all(
    const float* __restrict__ s_img, const float* __restrict__ s_qkv,
    const float* __restrict__ s_o,   const float* __restrict__ s_ff1,
    const float* __restrict__ s_ff2, const float* __restrict__ s_cls,
    unsigned short* __restrict__ d_img, unsigned short* __restrict__ d_qkv,
    unsigned short* __restrict__ d_o,   unsigned short* __restrict__ d_ff1,
    unsigned short* __restrict__ d_ff2, unsigned short* __restrict__ d_cls) {
  int bid = blockIdx.x;
  const float* src; unsigned short* dst; int K, N, Npad, rel;
  if (bid < 1024)       { src = s_img; dst = d_img; K = 4096; N = 1024; Npad = 1024; rel = bid; }
  else if (bid < 2560)  { rel = bid - 1024; int l = rel / 384; rel -= l * 384;
                          src = s_qkv + (size_t)l * 1024 * 1536; dst = d_qkv + (size_t)l * 1536 * 1024;
                          K = 1024; N = 1536; Npad = 1536; }
  else if (bid < 3072)  { rel = bid - 2560; int l = rel / 128; rel -= l * 128;
                          src = s_o   + (size_t)l * 512 * 1024;  dst = d_o   + (size_t)l * 1024 * 512;
                          K = 512;  N = 1024; Npad = 1024; }
  else if (bid < 4096)  { rel = bid - 3072; int l = rel / 256; rel -= l * 256;
                          src = s_ff1 + (size_t)l * 1024 * 1024; dst = d_ff1 + (size_t)l * 1024 * 1024;
                          K = 1024; N = 1024; Npad = 1024; }
  else if (bid < 5120)  { rel = bid - 4096; int l = rel / 256; rel -= l * 256;
                          src = s_ff2 + (size_t)l * 1024 * 1024; dst = d_ff2 + (size_t)l * 1024 * 1024;
                          K = 1024; N = 1024; Npad = 1024; }
  else                  { rel = bid - 5120; src = s_cls; dst = d_cls; K = 8192; N = 1000; Npad = 1024; }
  int tilesX = Npad >> 6;
  int nx = rel % tilesX, ky = rel / tilesX;
  int n0 = nx << 6, k0 = ky << 6;
  __shared__ float tile[64][65];
  int t = threadIdx.x;
#pragma unroll
  for (int i = 0; i < 4; ++i) {
    int slot = t + i * 256;
    int kk = slot >> 4, cq = slot & 15;
    int n = n0 + cq * 4;
    float4 v;
    if (n + 3 < N) v = *(const float4*)(src + (size_t)(k0 + kk) * N + n);
    else {
      v.x = v.y = v.z = v.w = 0.0f;
      if (n < N)     v.x = src[(size_t)(k0 + kk) * N + n];
      if (n + 1 < N) v.y = src[(size_t)(k0 + kk) * N + n + 1];
      if (n + 2 < N) v.z = src[(size_t)(k0 + kk) * N + n + 2];
      if (n + 3 < N) v.w = src[(size_t)(k0 + kk) * N + n + 3];
    }
    tile[kk][cq * 4 + 0] = v.x;
    tile[kk][cq * 4 + 1] = v.y;
    tile[kk][cq * 4 + 2] = v.z;
    tile[kk][cq * 4 + 3] = v.w;
  }
  __syncthreads();
#pragma unroll
  for (int i = 0; i < 4; ++i) {
    int slot = t + i * 256;
    int n = slot >> 4, kq = slot & 15;
    u16x4 o;
    o.x = f2bf(tile[kq * 4 + 0][n]);
    o.y = f2bf(tile[kq * 4 + 1][n]);
    o.z = f2bf(tile[kq * 4 + 2][n]);
    o.w = f2bf(tile[kq * 4 + 3][n]);
    *(u16x4*)(dst + (size_t)(n0 + n) * K + k0 + kq * 4) = o;
  }
}

// ---------- crop + *128 -> feats bf16 [256][4096] ----------
__global__ void crop_kernel(const float* __restrict__ x, const float* __restrict__ tr,
                            unsigned short* __restrict__ feats) {
  int b = blockIdx.x;
  __shared__ int xi[64], yi[64];
  float px = tr[b * 4 + 0], py = tr[b * 4 + 1], zx = tr[b * 4 + 2], zy = tr[b * 4 + 3];
  float x1 = __fmul_rn(px, 448.0f);
  float y1 = __fmul_rn(py, 448.0f);
  float xs = fminf(__fsub_rn(512.0f, x1), __fadd_rn(__fmul_rn(zx, 448.0f), 64.0f));
  float ys = fminf(__fsub_rn(512.0f, y1), __fadd_rn(__fmul_rn(zy, 448.0f), 64.0f));
  int t = threadIdx.x;
  if (t < 64) {
    float u = __fmul_rn(__fmul_rn((float)t, 0.015625f), xs);
    int v = (int)(__fadd_rn(floorf(u), x1));
    xi[t] = min(max(v, 0), 511);
  } else if (t < 128) {
    int tt = t - 64;
    float u = __fmul_rn(__fmul_rn((float)tt, 0.015625f), ys);
    int v = (int)(__fadd_rn(floorf(u), y1));
    yi[tt] = min(max(v, 0), 511);
  }
  __syncthreads();
  const float* img = x + (size_t)b * 262144;
  for (int p = t; p < 4096; p += 256) {
    int i = p >> 6, j = p & 63;
    float val = img[xi[i] * 512 + yi[j]] * 128.0f;
    feats[(size_t)b * 4096 + p] = f2bf(val);
  }
}

// ---------- z init: z[b][i][:] = history[i+1][b][:] for i<7 ----------
__global__ void zinit_kernel(const float* __restrict__ hist, float* __restrict__ z) {
  int idx = blockIdx.x * 256 + threadIdx.x;
  int off = idx * 4;
  int b = off / 7168;
  int r = off - b * 7168;
  int i = r >> 10, c = r & 1023;
  float4 v = *(const float4*)(hist + (size_t)(i + 1) * 262144 + (size_t)b * 1024 + c);
  *(float4*)(z + (size_t)b * 8192 + i * 1024 + c) = v;
}

// ---------- LayerNorm: z f32 [2048][1024] -> h bf16 (wave per row) ----------
__global__ __launch_bounds__(256) void ln_kernel(const float* __restrict__ z,
                                                 const float* __restrict__ sc,
                                                 const float* __restrict__ bi,
                                                 unsigned short* __restrict__ h) {
  int row = blockIdx.x * 4 + (threadIdx.x >> 6);
  int lane = threadIdx.x & 63;
  const float* zr = z + (size_t)row * 1024;
  float4 v[4];
  float s = 0.f, q = 0.f;
#pragma unroll
  for (int i = 0; i < 4; i++) {
    v[i] = *(const float4*)(zr + lane * 4 + i * 256);
    s += v[i].x + v[i].y + v[i].z + v[i].w;
    q += v[i].x * v[i].x + v[i].y * v[i].y + v[i].z * v[i].z + v[i].w * v[i].w;
  }
#pragma unroll
  for (int off = 32; off; off >>= 1) { s += __shfl_xor(s, off); q += __shfl_xor(q, off); }
  float mean = s * (1.0f / 1024.0f);
  float var = q * (1.0f / 1024.0f) - mean * mean;
  float rstd = rsqrtf(var + 1e-5f);
  u16x4* out = (u16x4*)(h + (size_t)row * 1024);
#pragma unroll
  for (int i = 0; i < 4; i++) {
    int c = lane * 4 + i * 256;
    float4 sv = *(const float4*)(sc + c);
    float4 bv = *(const float4*)(bi + c);
    u16x4 o;
    o.x = f2bf((v[i].x - mean) * rstd * sv.x + bv.x);
    o.y = f2bf((v[i].y - mean) * rstd * sv.y + bv.y);
    o.z = f2bf((v[i].z - mean) * rstd * sv.z + bv.z);
    o.w = f2bf((v[i].w - mean) * rstd * sv.w + bv.w);
    out[lane + i * 64] = o;
  }
}

// ---------- tiny attention: per (b,head), S=8, D=64, bf16 in/out ----------
__global__ __launch_bounds__(64) void attn_kernel(const unsigned short* __restrict__ qkv,
                                                  unsigned short* __restrict__ obuf) {
  int bh = blockIdx.x;
  int b = bh >> 3, hh = bh & 7;
  const unsigned short* base = qkv + (size_t)b * 8 * 1536;
  __shared__ float Q[8][64], K[8][64], V[8][64], S[8][8], P[8][8];
  int t = threadIdx.x;
#pragma unroll
  for (int i = 0; i < 8; i++) {
    Q[i][t] = bf2f(base[i * 1536 + hh * 64 + t]);
    K[i][t] = bf2f(base[i * 1536 + 512 + hh * 64 + t]);
    V[i][t] = bf2f(base[i * 1536 + 1024 + hh * 64 + t]);
  }
  __syncthreads();
  {
    int i = t >> 3, j = t & 7;
    float s = 0.f;
#pragma unroll
    for (int d = 0; d < 64; d++) s += Q[i][d] * K[j][d];
    S[i][j] = s * 0.125f;
  }
  __syncthreads();
  {
    int i = t >> 3, j = t & 7;
    float m = S[i][0];
#pragma unroll
    for (int jj = 1; jj < 8; jj++) m = fmaxf(m, S[i][jj]);
    float sum = 0.f;
#pragma unroll
    for (int jj = 0; jj < 8; jj++) sum += expf(S[i][jj] - m);
    P[i][j] = expf(S[i][j] - m) / sum;
  }
  __syncthreads();
#pragma unroll
  for (int i = 0; i < 8; i++) {
    float o = 0.f;
#pragma unroll
    for (int j = 0; j < 8; j++) o += P[i][j] * V[j][t];
    obuf[(size_t)(b * 8 + i) * 512 + hh * 64 + t] = f2bf(o);
  }
}

// ---------- bf16 MFMA GEMM, 128xTN tile, BK=64 ----------
template <int ITERS>
__device__ __forceinline__ void stage_tile(const unsigned short* __restrict__ g, int ld,
                                           int k0, char* lbase, int tid) {
#pragma unroll
  for (int it = 0; it < ITERS; ++it) {
    int c = tid + it * 256;              // 16B chunk id; 8 chunks per 64-k row
    int r = c >> 3;
    int c8 = (c & 7) ^ (r & 7);          // pre-swizzled global source (m173 pattern)
    const unsigned short* src = g + (size_t)r * ld + (k0 + c8 * 8);
    char* dst = lbase + c * 16;          // linear LDS dest: base + lane*16
    __builtin_amdgcn_global_load_lds((__attribute__((address_space(1))) void*)src,
                                     (__attribute__((address_space(3))) void*)dst, 16, 0, 0);
  }
}

__device__ __forceinline__ bf16x8 ld_frag(const char* base, int row, int k8) {
  int off = (row << 7) + ((k8 ^ (row & 7)) << 4);   // XOR swizzle (G4)
  return *(const bf16x8*)(base + off);
}

// TN=64:  4 waves, wave owns 32x64 (acc[2][4]); LDS 24KB/buf; grid.x = N/64
// TN=128: 4 waves, wave owns 64x64 (acc[4][4]); LDS 32KB/buf; grid.x = N/128
template <int TN, int ACT, bool OBF, bool RES, bool OBOTH>
__global__ __launch_bounds__(256) void gemm128(
    const unsigned short* __restrict__ A, int lda,
    const unsigned short* __restrict__ BT, int ldb,
    int Kloop, const float* __restrict__ bias, const float* __restrict__ res,
    float* __restrict__ outF, unsigned short* __restrict__ outB,
    int ldC, int Nstore, int partStride) {
  constexpr int MR = (TN == 64) ? 2 : 4;
  constexpr int BBY = TN * 128;                      // B bytes per buffer
  __shared__ __align__(16) char smem[2][16384 + BBY];
  const int tid = threadIdx.x;
  const int lane = tid & 63;
  const int wid = tid >> 6;
  const int rowbase = (TN == 64) ? wid * 32 : (wid >> 1) * 64;
  const int colbase = (TN == 64) ? 0 : (wid & 1) * 64;
  const int m0 = blockIdx.y << 7, n0 = blockIdx.x * TN;
  const int koff = blockIdx.z * Kloop;
  const unsigned short* Ag = A + (size_t)m0 * lda + koff;
  const unsigned short* Bg = BT + (size_t)n0 * ldb + koff;
  float* outFb = outF ? outF + (size_t)blockIdx.z * partStride : outF;
  f32x4 acc[MR][4];
#pragma unroll
  for (int m = 0; m < MR; m++)
#pragma unroll
    for (int n = 0; n < 4; n++) acc[m][n] = 0.f;
  const int nt = Kloop >> 6;
  stage_tile<4>(Ag, lda, 0, smem[0], tid);
  stage_tile<TN / 32>(Bg, ldb, 0, smem[0] + 16384, tid);
  __syncthreads();
  int cur = 0;
  const int rA = lane & 15, kq = lane >> 4;
  for (int t = 0; t < nt; ++t) {
    if (t + 1 < nt) {
      stage_tile<4>(Ag, lda, (t + 1) << 6, smem[cur ^ 1], tid);
      stage_tile<TN / 32>(Bg, ldb, (t + 1) << 6, smem[cur ^ 1] + 16384, tid);
    }
    const char* la = smem[cur];
    const char* lb = smem[cur] + 16384;
#pragma unroll
    for (int kk = 0; kk < 2; ++kk) {
      int k8 = kk * 4 + kq;
      bf16x8 af[MR], bfr[4];
#pragma unroll
      for (int m = 0; m < MR; m++) af[m] = ld_frag(la, rowbase + m * 16 + rA, k8);
#pragma unroll
      for (int n = 0; n < 4; n++) bfr[n] = ld_frag(lb, colbase + n * 16 + rA, k8);
#pragma unroll
      for (int m = 0; m < MR; m++)
#pragma unroll
        for (int n = 0; n < 4; n++)
          acc[m][n] = __builtin_amdgcn_mfma_f32_16x16x32_bf16(af[m], bfr[n], acc[m][n], 0, 0, 0);
    }
    __syncthreads();
    cur ^= 1;
  }
  const int rb = m0 + rowbase + (kq << 2);
  const int cb = n0 + colbase + rA;
#pragma unroll
  for (int m = 0; m < MR; m++)
#pragma unroll
    for (int n = 0; n < 4; n++) {
      int cg = cb + n * 16;
      if (cg >= Nstore) continue;
      float bv = bias ? bias[cg] : 0.0f;
#pragma unroll
      for (int j = 0; j < 4; j++) {
        int rg = rb + m * 16 + j;
        float v = acc[m][n][j] + bv;
        if (RES) v += res[(size_t)rg * ldC + cg];
        if (ACT == 1) v = 0.5f * v * (1.0f + erff(v * 0.70710678118654752f));
        if (OBOTH) {
          outFb[(size_t)rg * ldC + cg] = v;
          outB[(size_t)rg * ldC + cg] = f2bf(v);
        } else if (OBF) {
          outB[(size_t)rg * ldC + cg] = f2bf(v);
        } else {
          outFb[(size_t)rg * ldC + cg] = v;
        }
      }
    }
}

// ---------- split-K reduce: sum partials [nparts][256][1024] + bias -> dst ----------
__global__ __launch_bounds__(256) void reduceK(const float* __restrict__ part, int partStride,
                                               int nparts, const float* __restrict__ bias,
                                               float* __restrict__ dst, int ldDst, int Nstore) {
  int m = blockIdx.x;
  int c = threadIdx.x * 4;
  float4 a = {0.f, 0.f, 0.f, 0.f};
  for (int p = 0; p < nparts; ++p) {
    float4 v = *(const float4*)(part + (size_t)p * partStride + m * 1024 + c);
    a.x += v.x; a.y += v.y; a.z += v.z; a.w += v.w;
  }
  float4 bv = *(const float4*)(bias + c);
  a.x += bv.x; a.y += bv.y; a.z += bv.z; a.w += bv.w;
  if (c >= Nstore) return;
  float* drow = dst + (size_t)m * ldDst;
  if (c + 3 < Nstore) {
    *(float4*)(drow + c) = a;
  } else {
    float vals[4] = {a.x, a.y, a.z, a.w};
    for (int i = 0; i < 4 && c + i < Nstore; ++i) drow[c + i] = vals[i];
  }
}

// ---------- transform head: sigmoid(z_flat @ w_tr + b_tr), N=4, K=8192 ----------
__global__ __launch_bounds__(256) void trhead_kernel(const float* __restrict__ z,
                                                     const float* __restrict__ w,
                                                     const float* __restrict__ bt,
                                                     float* __restrict__ out) {
  int b = blockIdx.x;
  int t = threadIdx.x;
  const float* row = z + (size_t)b * 8192;
  float a0 = 0.f, a1 = 0.f, a2 = 0.f, a3 = 0.f;
  for (int k = t; k < 8192; k += 256) {
    float xv = row[k];
    const float* wr = w + (size_t)k * 4;
    a0 += xv * wr[0]; a1 += xv * wr[1]; a2 += xv * wr[2]; a3 += xv * wr[3];
  }
  __shared__ float red[256][4];
  red[t][0] = a0; red[t][1] = a1; red[t][2] = a2; red[t][3] = a3;
  __syncthreads();
  for (int s = 128; s > 0; s >>= 1) {
    if (t < s) {
#pragma unroll
      for (int o = 0; o < 4; o++) red[t][o] += red[t + s][o];
    }
    __syncthreads();
  }
  if (t < 4) {
    float v = red[0][t] + bt[t];
    out[256000 + b * 4 + t] = 1.0f / (1.0f + expf(-v));
  }
}

// ---------- launch ----------
extern "C" void kernel_launch(void* const* d_in, const int* in_sizes, int n_in,
                              void* d_out, int out_size, void* d_ws, size_t ws_size,
                              hipStream_t stream) {
  const float* x      = (const float*)d_in[0];
  const float* tr     = (const float*)d_in[1];
  const float* hist   = (const float*)d_in[2];
  const float* w_img  = (const float*)d_in[3];
  const float* b_img  = (const float*)d_in[4];
  const float* ln1_s  = (const float*)d_in[5];
  const float* ln1_b  = (const float*)d_in[6];
  const float* w_qkv  = (const float*)d_in[7];
  const float* w_o    = (const float*)d_in[8];
  const float* b_o    = (const float*)d_in[9];
  const float* ln2_s  = (const float*)d_in[10];
  const float* ln2_b  = (const float*)d_in[11];
  const float* w_ff1  = (const float*)d_in[12];
  const float* b_ff1  = (const float*)d_in[13];
  const float* w_ff2  = (const float*)d_in[14];
  const float* b_ff2  = (const float*)d_in[15];
  const float* w_cls  = (const float*)d_in[16];
  const float* b_cls  = (const float*)d_in[17];
  const float* w_tr   = (const float*)d_in[18];
  const float* b_tr   = (const float*)d_in[19];
  float* outF = (float*)d_out;

  char* w = (char*)d_ws;
  auto alloc = [&](size_t bytes) { char* p = w; w += (bytes + 255) & ~(size_t)255; return p; };
  unsigned short* BT_img = (unsigned short*)alloc((size_t)1024 * 4096 * 2);
  unsigned short* BT_qkv = (unsigned short*)alloc((size_t)4 * 1536 * 1024 * 2);
  unsigned short* BT_o   = (unsigned short*)alloc((size_t)4 * 1024 * 512 * 2);
  unsigned short* BT_ff1 = (unsigned short*)alloc((size_t)4 * 1024 * 1024 * 2);
  unsigned short* BT_ff2 = (unsigned short*)alloc((size_t)4 * 1024 * 1024 * 2);
  unsigned short* BT_cls = (unsigned short*)alloc((size_t)1024 * 8192 * 2);
  unsigned short* feats  = (unsigned short*)alloc((size_t)256 * 4096 * 2);
  float*          z      = (float*)alloc((size_t)2048 * 1024 * 4);
  unsigned short* h      = (unsigned short*)alloc((size_t)2048 * 1024 * 2);  // also tl
  unsigned short* qkvb   = (unsigned short*)alloc((size_t)2048 * 1536 * 2);
  unsigned short* obuf   = (unsigned short*)alloc((size_t)2048 * 512 * 2);
  unsigned short* g      = (unsigned short*)alloc((size_t)2048 * 1024 * 2);
  float*          part   = (float*)alloc((size_t)8 * 256 * 1024 * 4);
  if ((size_t)(w - (char*)d_ws) > ws_size) return;

  wcast_all<<<7168, 256, 0, stream>>>(w_img, w_qkv, w_o, w_ff1, w_ff2, w_cls,
                                      BT_img, BT_qkv, BT_o, BT_ff1, BT_ff2, BT_cls);
  crop_kernel<<<256, 256, 0, stream>>>(x, tr, feats);
  zinit_kernel<<<1792, 256, 0, stream>>>(hist, z);

  // image_latent: [256,4096]@[4096,1024] split-K x8 (Kc=512) -> part -> z[:,7,:]
  gemm128<64, 0, false, false, false><<<dim3(16, 2, 8), 256, 0, stream>>>(
      feats, 4096, BT_img, 4096, 512, nullptr, nullptr, part, nullptr, 1024, 1024, 262144);
  reduceK<<<256, 256, 0, stream>>>(part, 262144, 8, b_img, z + 7168, 8192, 1024);

  for (int i = 0; i < 4; ++i) {
    ln_kernel<<<512, 256, 0, stream>>>(z, ln1_s + i * 1024, ln1_b + i * 1024, h);
    gemm128<128, 0, true, false, false><<<dim3(12, 16), 256, 0, stream>>>(
        h, 1024, BT_qkv + (size_t)i * 1536 * 1024, 1024, 1024,
        nullptr, nullptr, nullptr, qkvb, 1536, 1536, 0);
    attn_kernel<<<2048, 64, 0, stream>>>(qkvb, obuf);
    gemm128<64, 0, false, true, false><<<dim3(16, 16), 256, 0, stream>>>(
        obuf, 512, BT_o + (size_t)i * 1024 * 512, 512, 512,
        b_o + i * 1024, z, z, nullptr, 1024, 1024, 0);
    ln_kernel<<<512, 256, 0, stream>>>(z, ln2_s + i * 1024, ln2_b + i * 1024, h);
    gemm128<64, 1, true, false, false><<<dim3(16, 16), 256, 0, stream>>>(
        h, 1024, BT_ff1 + (size_t)i * 1024 * 1024, 1024, 1024,
        b_ff1 + i * 1024, nullptr, nullptr, g, 1024, 1024, 0);
    if (i < 3) {
      gemm128<64, 0, false, true, false><<<dim3(16, 16), 256, 0, stream>>>(
          g, 1024, BT_ff2 + (size_t)i * 1024 * 1024, 1024, 1024,
          b_ff2 + i * 1024, z, z, nullptr, 1024, 1024, 0);
    } else {
      // final layer: write z (f32) AND tl (bf16) in one epilogue
      gemm128<64, 0, false, true, true><<<dim3(16, 16), 256, 0, stream>>>(
          g, 1024, BT_ff2 + (size_t)i * 1024 * 1024, 1024, 1024,
          b_ff2 + i * 1024, z, z, h, 1024, 1024, 0);
    }
  }

  // cls: [256,8192]@[8192,1024pad] split-K x8 (Kc=1024) -> part -> outF[:,:1000]
  gemm128<64, 0, false, false, false><<<dim3(16, 2, 8), 256, 0, stream>>>(
      h, 8192, BT_cls, 8192, 1024, nullptr, nullptr, part, nullptr, 1024, 1024, 262144);
  reduceK<<<256, 256, 0, stream>>>(part, 262144, 8, b_cls, outF, 1000, 1000);
  trhead_kernel<<<256, 256, 0, stream>>>(z, w_tr, b_tr, outF);
}